// Round 3
// baseline (122.838 us; speedup 1.0000x reference)
//
#include <hip/hip_runtime.h>
#include <hip/hip_bf16.h>
#include <math.h>

// MultiHeadAttentionQuantum, B=2048 S=1 E=1024 H=128 DK=NW=8
// All inputs/outputs float32.
//
// Algebra: S==1 -> attention out == v = x @ Wv^T (wq,wk dead).
// RX compose additively; CNOTs are XOR basis permutations ->
//   t_j = cos(v_j + rx_j);  qout[0]=t1*...*t7;  qout[w>=1]=t0*...*tw
// out = qout @ Wc^T + bc
//
// R9 (split-K) and R10 (counted-vmcnt 3-deep pipeline): both neutral ->
// the GEMM K-loop is not the binding term. R11: remove the cvt3 dispatch
// entirely (3 -> 2 kernels). GEMM1 consumes x/wv in f32 with in-flight
// cvt during reg-staging (same RNE rounding -> bit-identical output) and
// converts wc->wcb as an epilogue side job. GEMM2 is the proven bf16
// split-K kernel, untouched.

#define BB 2048
#define EN 1024

typedef short s16x8 __attribute__((ext_vector_type(8)));
typedef short s16x4 __attribute__((ext_vector_type(4)));
typedef float f32x4 __attribute__((ext_vector_type(4)));

union Frag  { s16x8 v; __hip_bfloat16 h[8]; };
union Half4 { s16x4 v; __hip_bfloat16 h[4]; };

__device__ inline s16x8 cvt_frag(f32x4 lo, f32x4 hi) {
    Frag u;
    #pragma unroll
    for (int j = 0; j < 4; ++j) {
        u.h[j]     = __float2bfloat16(lo[j]);
        u.h[4 + j] = __float2bfloat16(hi[j]);
    }
    return u.v;
}

// async 16B/lane global -> LDS (lds base wave-uniform; HW adds lane*16)
__device__ inline void gll16(const __hip_bfloat16* g, __hip_bfloat16* l) {
    __builtin_amdgcn_global_load_lds(
        (const __attribute__((address_space(1))) void*)g,
        (__attribute__((address_space(3))) void*)l,
        16, 0, 0);
}

// ---------------------------------------------------------------------------
// GEMM1: V' = x @ wv^T (f32 inputs, in-flight cvt to bf16), quantum epilogue
// -> bf16 V. Side job: wc (f32) -> wcb (bf16), 4 elems/thread.
// Tile 64x64, 512 thr = 8 waves (4m x 2n), wave tile 16x32, BK=64,
// double-buffered frag-ordered bf16 LDS (32 KB): frag-tile = 512 elems
// (16 rows x 32 k), lane l's fragment at tile_base + l*8. A tile (mt,kt)
// at (mt*2+kt)*512; B tile (nt,kt) at 4096+(nt*2+kt)*512.
// Staging: thread owns frag-tiles t = wave*2+i; per K-step loads 2x32B f32,
// cvt, one ds_write_b128 each. Plain HIP: compiler hoists the f32 loads to
// iteration top; __syncthreads provides the (single) barrier per step.
// ---------------------------------------------------------------------------
__global__ __launch_bounds__(512, 4) void gemm1_kernel(
        const float* __restrict__ A,    // x, 2048 x 1024 f32
        const float* __restrict__ W,    // wv, 1024 x 1024 f32
        const float* __restrict__ wc,   // 1024 x 1024 f32
        const float* __restrict__ rx,
        __hip_bfloat16* __restrict__ wcb,
        __hip_bfloat16* __restrict__ V)
{
    __shared__ __align__(16) unsigned char smem[33792];
    __hip_bfloat16* lds = (__hip_bfloat16*)smem;

    const int tid  = threadIdx.x;
    const int wave = tid >> 6, lane = tid & 63;
    const int l15 = lane & 15, lq = lane >> 4;
    const int m0 = blockIdx.x * 64, n0 = blockIdx.y * 64;
    const int wmt = wave >> 1;          // 0..3  (16-row wave tile)
    const int wnt = wave & 1;           // 0..1  (32-col wave tile)

    // staging: thread stages 2 of 16 frag-tiles: t = wave*2 + i
    const float* gsrc[2];
    int ldst[2];
    #pragma unroll
    for (int i = 0; i < 2; ++i) {
        const int t = wave * 2 + i;
        int row, lofs;
        const float* base;
        if (t < 8) { const int mt = t >> 1; row = m0 + mt * 16 + l15; base = A; lofs = t * 512; }
        else       { const int u = t - 8;   row = n0 + (u >> 1) * 16 + l15; base = W; lofs = 4096 + u * 512; }
        gsrc[i] = base + (size_t)row * EN + (t & 1) * 32 + lq * 8;
        ldst[i] = lofs + lane * 8;
    }

    f32x4 acc[2] = {};

    // prologue: stage step 0 into buf 0
    {
        f32x4 l0 = *(const f32x4*)(gsrc[0]);
        f32x4 h0 = *(const f32x4*)(gsrc[0] + 4);
        f32x4 l1 = *(const f32x4*)(gsrc[1]);
        f32x4 h1 = *(const f32x4*)(gsrc[1] + 4);
        *(s16x8*)&lds[ldst[0]] = cvt_frag(l0, h0);
        *(s16x8*)&lds[ldst[1]] = cvt_frag(l1, h1);
    }
    __syncthreads();

    int p = 0;
    for (int k0 = 64; k0 <= EN; k0 += 64) {
        f32x4 l0, h0, l1, h1;
        const bool pref = (k0 < EN);
        if (pref) {                      // loads for step k+1 (hoisted early)
            l0 = *(const f32x4*)(gsrc[0] + k0);
            h0 = *(const f32x4*)(gsrc[0] + k0 + 4);
            l1 = *(const f32x4*)(gsrc[1] + k0);
            h1 = *(const f32x4*)(gsrc[1] + k0 + 4);
        }
        const __hip_bfloat16* Ab = &lds[p * 8192];
        const __hip_bfloat16* Bb = Ab + 4096;
        #pragma unroll
        for (int kt = 0; kt < 2; ++kt) {
            s16x8 a = *(const s16x8*)&Ab[(wmt * 2 + kt) * 512 + lane * 8];
            #pragma unroll
            for (int j = 0; j < 2; ++j) {
                s16x8 b = *(const s16x8*)&Bb[((wnt * 2 + j) * 2 + kt) * 512 + lane * 8];
                acc[j] = __builtin_amdgcn_mfma_f32_16x16x32_bf16(a, b, acc[j], 0, 0, 0);
            }
        }
        if (pref) {                      // write step k+1 into buf q
            const int q = p ^ 1;
            *(s16x8*)&lds[q * 8192 + ldst[0]] = cvt_frag(l0, h0);
            *(s16x8*)&lds[q * 8192 + ldst[1]] = cvt_frag(l1, h1);
        }
        __syncthreads();
        p ^= 1;
    }

    // side job: this block's 2048-elem slice of wc -> wcb (4 f32/thread)
    {
        const int bf = blockIdx.y * gridDim.x + blockIdx.x;     // 0..511
        const size_t co = ((size_t)bf * 512 + tid) * 4;
        f32x4 w4 = *(const f32x4*)(wc + co);
        Half4 hh;
        #pragma unroll
        for (int j = 0; j < 4; ++j) hh.h[j] = __float2bfloat16(w4[j]);
        *(s16x4*)(wcb + co) = hh.v;
    }

    // quantum epilogue: acc -> LDS f32 64x68 -> cos/products -> bf16 V
    float* sb = (float*)smem;            // 17408 B, lds bufs dead (last sync done)
    #pragma unroll
    for (int j = 0; j < 2; ++j) {
        const int col = wnt * 32 + j * 16 + l15;
        #pragma unroll
        for (int r = 0; r < 4; ++r)
            sb[(wmt * 16 + lq * 4 + r) * 68 + col] = acc[j][r];
    }
    __syncthreads();
    const int row = tid >> 3, g = tid & 7;   // 64 rows x 8 groups
    const float* pv = &sb[row * 68 + g * 8];
    float t[8];
    #pragma unroll
    for (int j = 0; j < 8; ++j) t[j] = __cosf(pv[j] + rx[j]);
    Frag o;
    float suf = t[1];
    #pragma unroll
    for (int j = 2; j < 8; ++j) suf *= t[j];
    o.h[0] = __float2bfloat16(suf);
    float pr = t[0];
    #pragma unroll
    for (int j = 1; j < 8; ++j) { pr *= t[j]; o.h[j] = __float2bfloat16(pr); }
    *(s16x8*)(V + (size_t)(m0 + row) * EN + n0 + g * 8) = o.v;
}

// ---------------------------------------------------------------------------
// GEMM2: out = V @ wcb^T + bc (all bf16 operands). Proven structure:
// tile 64x64, 512 thr = 8 waves 2m x 2n x 2k (split-K, wave tile 32x32),
// THREE frag-ordered LDS buffers, 2-step-ahead global_load_lds prefetch,
// counted vmcnt, cross-k LDS reduction in epilogue.
// ---------------------------------------------------------------------------
__global__ __launch_bounds__(512, 4) void gemm2_kernel(
        const __hip_bfloat16* __restrict__ A,   // V bf16
        const __hip_bfloat16* __restrict__ W,   // wcb bf16
        const float* __restrict__ bias,
        float* __restrict__ C)
{
    __shared__ __align__(16) unsigned char smem[65536];
    __hip_bfloat16* lds = (__hip_bfloat16*)smem;

    const int tid  = threadIdx.x;
    const int wave = tid >> 6, lane = tid & 63;
    const int l15 = lane & 15, lq = lane >> 4;
    const int m0 = blockIdx.x * 64, n0 = blockIdx.y * 64;
    const int wk  = wave >> 2;          // 0..1: owned 32-k subtile per step
    const int wmn = wave & 3;
    const int wm  = wmn >> 1;           // 0..1  (32-row wave tile)
    const int wn  = wmn & 1;            // 0..1  (32-col wave tile)

    // staging: wave stages 2 of 16 frag-tiles: t = wave*2 + i
    const __hip_bfloat16* gsrc[2];
    int ldst[2];
    #pragma unroll
    for (int i = 0; i < 2; ++i) {
        const int t = wave * 2 + i;
        int row, lofs;
        const __hip_bfloat16* base;
        if (t < 8) { const int mt = t >> 1; row = m0 + mt * 16 + l15; base = A; lofs = t * 512; }
        else       { const int u = t - 8;   row = n0 + (u >> 1) * 16 + l15; base = W; lofs = 4096 + u * 512; }
        gsrc[i] = base + (size_t)row * EN + (t & 1) * 32 + lq * 8;
        ldst[i] = lofs;
    }

    f32x4 acc[2][2] = {};

    // prologue: prefetch steps 0 (buf0) and 1 (buf1)
    #pragma unroll
    for (int i = 0; i < 2; ++i) gll16(gsrc[i], &lds[ldst[i]]);
    #pragma unroll
    for (int i = 0; i < 2; ++i) gll16(gsrc[i] + 64, &lds[8192 + ldst[i]]);

    #pragma unroll
    for (int k = 0; k < 16; ++k) {
        if (k < 15) asm volatile("s_waitcnt vmcnt(2)" ::: "memory");
        else        asm volatile("s_waitcnt vmcnt(0)" ::: "memory");
        __builtin_amdgcn_s_barrier();
        __builtin_amdgcn_sched_barrier(0);
        if (k + 2 < 16) {
            const int qb = ((k + 2) % 3) * 8192;
            #pragma unroll
            for (int i = 0; i < 2; ++i)
                gll16(gsrc[i] + (k + 2) * 64, &lds[qb + ldst[i]]);
        }
        const __hip_bfloat16* Ab = &lds[(k % 3) * 8192];
        const __hip_bfloat16* Bb = Ab + 4096;
        s16x8 a[2], b[2];
        #pragma unroll
        for (int mi = 0; mi < 2; ++mi)
            a[mi] = *(const s16x8*)&Ab[((wm * 2 + mi) * 2 + wk) * 512 + lane * 8];
        #pragma unroll
        for (int nj = 0; nj < 2; ++nj)
            b[nj] = *(const s16x8*)&Bb[((wn * 2 + nj) * 2 + wk) * 512 + lane * 8];
        #pragma unroll
        for (int mi = 0; mi < 2; ++mi) {
            #pragma unroll
            for (int nj = 0; nj < 2; ++nj)
                acc[mi][nj] = __builtin_amdgcn_mfma_f32_16x16x32_bf16(
                    a[mi], b[nj], acc[mi][nj], 0, 0, 0);
        }
    }

    // cross-k reduction: wk=1 partials -> LDS, wk=0 waves add + bias + store.
    float* red = (float*)(smem + 49152);
    if (wk == 1) {
        #pragma unroll
        for (int mi = 0; mi < 2; ++mi) {
            #pragma unroll
            for (int nj = 0; nj < 2; ++nj)
                *(f32x4*)&red[((wmn * 2 + mi) * 2 + nj) * 256 + lane * 4] = acc[mi][nj];
        }
    }
    __syncthreads();

    if (wk == 0) {
        #pragma unroll
        for (int mi = 0; mi < 2; ++mi) {
            #pragma unroll
            for (int nj = 0; nj < 2; ++nj) {
                f32x4 o = *(const f32x4*)&red[((wmn * 2 + mi) * 2 + nj) * 256 + lane * 4];
                const int col = n0 + wn * 32 + nj * 16 + l15;
                const float bv = bias[col];
                #pragma unroll
                for (int r = 0; r < 4; ++r) {
                    const int row = m0 + wm * 32 + mi * 16 + lq * 4 + r;
                    C[(size_t)row * EN + col] = acc[mi][nj][r] + o[r] + bv;
                }
            }
        }
    }
}

extern "C" void kernel_launch(void* const* d_in, const int* in_sizes, int n_in,
                              void* d_out, int out_size, void* d_ws, size_t ws_size,
                              hipStream_t stream)
{
    // inputs: x, wq, wk, wv, wc, bc, rx_params (wq/wk dead: S==1)
    const float* x  = (const float*)d_in[0];
    const float* wv = (const float*)d_in[3];
    const float* wc = (const float*)d_in[4];
    const float* bc = (const float*)d_in[5];
    const float* rx = (const float*)d_in[6];
    float* out = (float*)d_out;

    const size_t WE = (size_t)EN * EN;   // 1M elems

    // ws (6 MB): [wcb 2MB | V 4MB]
    __hip_bfloat16* wcb = (__hip_bfloat16*)d_ws;
    __hip_bfloat16* V   = wcb + WE;

    dim3 grid(BB / 64, EN / 64);         // 32 x 16 = 512 blocks
    gemm1_kernel<<<grid, 512, 0, stream>>>(x, wv, wc, rx, wcb, V);
    gemm2_kernel<<<grid, 512, 0, stream>>>(V, wcb, bc, out);
}